// Round 12
// baseline (136.272 us; speedup 1.0000x reference)
//
#include <hip/hip_runtime.h>
#include <math.h>

#define N_OBJ 8192
#define N_SR  4096
#define N_F   4096
#define EPSF  1e-8f
#define EPS2F 1e-16f

typedef float v2f __attribute__((ext_vector_type(2)));
static __device__ __forceinline__ v2f sp(float x) { v2f r; r.x = x; r.y = x; return r; }
static __device__ __forceinline__ v2f vfma(v2f a, v2f b, v2f c) { return __builtin_elementwise_fma(a, b, c); }

// ================= K1: NN (chunked sr, packed fp32) + face table ============
// 1024 blocks x 256 (4 blocks/CU). Each block: 8 obj points; sr staged in 4
// chunks of 1024 (16 KB LDS, pair-packed SoA). Each wave owns 2 points.
// argmin on shifted d2' = ss - 2*dot; ascending global index across chunks
// preserves jnp.argmin first-min tie rule.
__global__ void __launch_bounds__(256) nn_all(const float* __restrict__ obj,
                                              const float* __restrict__ sr,
                                              const float* __restrict__ hv,
                                              const float* __restrict__ fn,
                                              const int* __restrict__ hf,
                                              float* __restrict__ out,
                                              float4* __restrict__ Dws,
                                              float4* __restrict__ F,
                                              int* __restrict__ done) {
    __shared__ float4 cXY[512];                    // (x0,x1,y0,y1)   8 KB
    __shared__ float4 cZS[512];                    // (z0,z1,ss0,ss1) 8 KB
    const int tid = threadIdx.x, b = blockIdx.x;
    const float2* sr2 = (const float2*)sr;

    if (b == 0 && tid == 0) done[0] = 0;
    if (tid < 4) {                                 // 4 faces per block
        const int f = b * 4 + tid;
        const int i0 = hf[3*f], i1 = hf[3*f+1], i2 = hf[3*f+2];
        const float v0x = hv[3*i0], v0y = hv[3*i0+1], v0z = hv[3*i0+2];
        const float v1x = hv[3*i1], v1y = hv[3*i1+1], v1z = hv[3*i1+2];
        const float v2x = hv[3*i2], v2y = hv[3*i2+1], v2z = hv[3*i2+2];
        const float nx = fn[3*f], ny = fn[3*f+1], nz = fn[3*f+2];
        F[4*f+0] = make_float4(nx, ny, nz, v0x*nx + v0y*ny + v0z*nz);
        {
            float ex = v1x-v0x, ey = v1y-v0y, ez = v1z-v0z;
            float cx = ny*ez-nz*ey, cy = nz*ex-nx*ez, cz = nx*ey-ny*ex;
            F[4*f+1] = make_float4(cx, cy, cz, v0x*cx + v0y*cy + v0z*cz);
        }
        {
            float ex = v2x-v1x, ey = v2y-v1y, ez = v2z-v1z;
            float cx = ny*ez-nz*ey, cy = nz*ex-nx*ez, cz = nx*ey-ny*ex;
            F[4*f+2] = make_float4(cx, cy, cz, v1x*cx + v1y*cy + v1z*cz);
        }
        {
            float ex = v0x-v2x, ey = v0y-v2y, ez = v0z-v2z;
            float cx = ny*ez-nz*ey, cy = nz*ex-nx*ez, cz = nx*ey-ny*ex;
            F[4*f+3] = make_float4(cx, cy, cz, v2x*cx + v2y*cy + v2z*cz);
        }
    }

    const int w = tid >> 6, lane = tid & 63;
    const int p0 = b * 8 + w * 2, p1 = p0 + 1;     // wave-uniform -> s_load

    const float ax = obj[3*p0], ay = obj[3*p0+1], az = obj[3*p0+2];
    const float bx = obj[3*p1], by = obj[3*p1+1], bz = obj[3*p1+2];
    const float aaa = fmaf(ax, ax, fmaf(ay, ay, az * az));
    const float aab = fmaf(bx, bx, fmaf(by, by, bz * bz));

    float a0 = INFINITY, a1 = INFINITY, c0v = INFINITY, c1v = INFINITY;
    int ai0 = 0, ai1 = 1, ci0 = 0, ci1 = 1;

    for (int c = 0; c < 4; ++c) {
        __syncthreads();                           // prev chunk fully consumed
        {
#pragma unroll
            for (int t = 0; t < 2; ++t) {
                int e = t * 256 + tid;             // 512 pairs per chunk
                int gp = c * 512 + e;
                float2 A = sr2[3 * gp], B = sr2[3 * gp + 1], C = sr2[3 * gp + 2];
                float x0 = A.x, y0 = A.y, z0 = B.x, x1 = B.y, y1 = C.x, z1 = C.y;
                cXY[e] = make_float4(x0, x1, y0, y1);
                cZS[e] = make_float4(z0, z1,
                                     fmaf(x0, x0, fmaf(y0, y0, z0 * z0)),
                                     fmaf(x1, x1, fmaf(y1, y1, z1 * z1)));
            }
        }
        __syncthreads();

        int e2 = c * 1024 + lane * 2;              // global idx of half-0
#pragma unroll
        for (int step = 0; step < 8; ++step) {
            int e = step * 64 + lane;
            float4 A = cXY[e];                     // 16B stride, conflict-free
            float4 B = cZS[e];
            v2f X; X.x = A.x; X.y = A.y;
            v2f Y; Y.x = A.z; Y.y = A.w;
            v2f Z; Z.x = B.x; Z.y = B.y;
            v2f SS; SS.x = B.z; SS.y = B.w;
            {
                v2f d  = vfma(Z, sp(az), vfma(Y, sp(ay), X * sp(ax)));
                v2f d2 = vfma(d, sp(-2.f), SS);
                bool q0 = d2.x < a0, q1 = d2.y < a1;
                a0 = q0 ? d2.x : a0;  ai0 = q0 ? e2     : ai0;
                a1 = q1 ? d2.y : a1;  ai1 = q1 ? e2 + 1 : ai1;
            }
            {
                v2f d  = vfma(Z, sp(bz), vfma(Y, sp(by), X * sp(bx)));
                v2f d2 = vfma(d, sp(-2.f), SS);
                bool q0 = d2.x < c0v, q1 = d2.y < c1v;
                c0v = q0 ? d2.x : c0v;  ci0 = q0 ? e2     : ci0;
                c1v = q1 ? d2.y : c1v;  ci1 = q1 ? e2 + 1 : ci1;
            }
            e2 += 128;
        }
    }

    float bdA = a0; int biA = ai0;
    if (a1 < bdA || (a1 == bdA && ai1 < biA)) { bdA = a1; biA = ai1; }
    float bdB = c0v; int biB = ci0;
    if (c1v < bdB || (c1v == bdB && ci1 < biB)) { bdB = c1v; biB = ci1; }
#pragma unroll
    for (int off = 32; off > 0; off >>= 1) {
        float d = __shfl_down(bdA, off);
        int   i = __shfl_down(biA, off);
        if (d < bdA || (d == bdA && i < biA)) { bdA = d; biA = i; }
        float e = __shfl_down(bdB, off);
        int   j = __shfl_down(biB, off);
        if (e < bdB || (e == bdB && j < biB)) { bdB = e; biB = j; }
    }
    if (lane == 0) {
        {
            float dx = sr[3*biA] - ax, dy = sr[3*biA+1] - ay, dz = sr[3*biA+2] - az;
            Dws[p0] = make_float4(dx, dy, dz, fmaf(dx, dx, fmaf(dy, dy, dz * dz)));
            float nn  = sqrtf(fmaxf(bdA + aaa, 0.f));
            float sig = 1.f / (1.f + expf(-100.f * nn));
            out[1 + p0] = 1.f - 2.f * (sig - 0.5f);
        }
        {
            float dx = sr[3*biB] - bx, dy = sr[3*biB+1] - by, dz = sr[3*biB+2] - bz;
            Dws[p1] = make_float4(dx, dy, dz, fmaf(dx, dx, fmaf(dy, dy, dz * dz)));
            float nn  = sqrtf(fmaxf(bdB + aab, 0.f));
            float sig = 1.f / (1.f + expf(-100.f * nn));
            out[1 + p1] = 1.f - 2.f * (sig - 0.5f);
        }
    }
}

// ================= K2: ray parity + fused last-block pen_dist ===============
// 512 blocks = 8 pt-groups x 64 face-chunks (RFC=64, 4 KB LDS).
// 4 CONSECUTIVE points/thread: obj = 3 coalesced float4 loads; the 4 counts
// pack into one u32 store (word layout == byte layout pcount[fc][pt]).
// Sign-squared hit test (d2=denom^2>0, nd=num*denom):
//   |denom|>EPS <=> d2>EPS^2 ; t>EPS <=> nd-EPS*d2>0 ;
//   e_i>=0 <=> q_i = C_i.(o*d2 + nd*D) - s_i*d2 >= 0
// Last-arriving block (done-counter, no spin) reduces: parity of a sum =
// XOR of parities -> byte-parallel XOR over chunk words, then deterministic
// pen_dist sum. Agent-scope atomic loads dodge stale per-XCD L2.
#define RFC 64
#define RAY_NB 512
__global__ void __launch_bounds__(256) ray_count(const float* __restrict__ obj,
                                                 const float4* __restrict__ Dws,
                                                 const float4* __restrict__ F,
                                                 unsigned* __restrict__ pcount32,
                                                 int* __restrict__ done,
                                                 float* __restrict__ out) {
    __shared__ float4 sF[RFC * 4];                 // 4 KB
    __shared__ float wsum[4];
    __shared__ int lastf;
    const int tid = threadIdx.x;
    const int pg = blockIdx.x & 7, fc = blockIdx.x >> 3;

    sF[tid] = (F + (size_t)fc * RFC * 4)[tid];     // 256 float4 = 64 faces

    float px[4], py[4], pz[4], qx[4], qy[4], qz[4];
    int cnt[4];
    {
        const float4* obj4 = (const float4*)obj;   // (pg*1024+tid*4)*3 floats, 16B-aligned
        int base = pg * 768 + tid * 3;
        float4 A = obj4[base], B = obj4[base + 1], C = obj4[base + 2];
        px[0] = A.x; py[0] = A.y; pz[0] = A.z;
        px[1] = A.w; py[1] = B.x; pz[1] = B.y;
        px[2] = B.z; py[2] = B.w; pz[2] = C.x;
        px[3] = C.y; py[3] = C.z; pz[3] = C.w;
        int p4 = pg * 1024 + tid * 4;
#pragma unroll
        for (int h = 0; h < 4; ++h) {
            float4 D = Dws[p4 + h];
            qx[h] = D.x; qy[h] = D.y; qz[h] = D.z;
            cnt[h] = 0;
        }
    }
    __syncthreads();

    float4 nF0 = sF[0], nF1 = sF[1], nF2 = sF[2], nF3 = sF[3];
#pragma unroll 4
    for (int f = 0; f < RFC; ++f) {
        const float4 Fn = nF0, C1 = nF1, C2 = nF2, C3 = nF3;
        if (f + 1 < RFC) {                         // one-face register lookahead
            nF0 = sF[4*f+4]; nF1 = sF[4*f+5]; nF2 = sF[4*f+6]; nF3 = sF[4*f+7];
        }
#pragma unroll
        for (int h = 0; h < 4; ++h) {
            float denom = fmaf(Fn.z, qz[h], fmaf(Fn.y, qy[h], Fn.x * qx[h]));
            float num   = Fn.w - fmaf(Fn.z, pz[h], fmaf(Fn.y, py[h], Fn.x * px[h]));
            float d2 = denom * denom;
            float nd = num * denom;
            float wx = fmaf(px[h], d2, nd * qx[h]);
            float wy = fmaf(py[h], d2, nd * qy[h]);
            float wz = fmaf(pz[h], d2, nd * qz[h]);
            float q1 = fmaf(-C1.w, d2, fmaf(C1.z, wz, fmaf(C1.y, wy, C1.x * wx)));
            float q2 = fmaf(-C2.w, d2, fmaf(C2.z, wz, fmaf(C2.y, wy, C2.x * wx)));
            float q3 = fmaf(-C3.w, d2, fmaf(C3.z, wz, fmaf(C3.y, wy, C3.x * wx)));
            float tc = fmaf(-EPSF, d2, nd);        // t > EPS
            float dc = d2 - EPS2F;                 // |denom| > EPS
            float m  = fminf(fminf(q1, q2), fminf(q3, fminf(tc, dc)));
            cnt[h] += (m >= 0.f) ? 1 : 0;
        }
    }
    pcount32[(size_t)fc * 2048 + pg * 256 + tid] =
        (unsigned)cnt[0] | ((unsigned)cnt[1] << 8) |
        ((unsigned)cnt[2] << 16) | ((unsigned)cnt[3] << 24);

    // ---- fused last-block finalize (deterministic) ----
    __syncthreads();                               // drains this block's stores
    if (tid == 0) {
        __threadfence();                           // release: flush to coherence pt
        lastf = (atomicAdd(done, 1) == RAY_NB - 1) ? 1 : 0;
    }
    __syncthreads();
    if (!lastf) return;
    __threadfence();                               // acquire

    float s = 0.f;
#pragma unroll
    for (int it = 0; it < 8; ++it) {
        int wi = it * 256 + tid;                   // word = 4 consecutive points
        unsigned x = 0;
#pragma unroll 8
        for (int fcc = 0; fcc < 64; ++fcc)
            x ^= __hip_atomic_load(&pcount32[fcc * 2048 + wi],
                                   __ATOMIC_RELAXED, __HIP_MEMORY_SCOPE_AGENT);
        int p4 = wi * 4;
        if (x & 0x01u)        s += Dws[p4 + 0].w;  // bit0 of each byte = parity
        if (x & 0x0100u)      s += Dws[p4 + 1].w;
        if (x & 0x010000u)    s += Dws[p4 + 2].w;
        if (x & 0x01000000u)  s += Dws[p4 + 3].w;
    }
#pragma unroll
    for (int off = 32; off > 0; off >>= 1) s += __shfl_down(s, off);
    if ((tid & 63) == 0) wsum[tid >> 6] = s;
    __syncthreads();
    if (tid == 0)
        out[0] = sqrtf(wsum[0] + wsum[1] + wsum[2] + wsum[3] + 1e-12f);
}

extern "C" void kernel_launch(void* const* d_in, const int* in_sizes, int n_in,
                              void* d_out, int out_size, void* d_ws, size_t ws_size,
                              hipStream_t stream) {
    const float* obj = (const float*)d_in[0];
    const float* sr  = (const float*)d_in[1];
    const float* hv  = (const float*)d_in[2];
    const float* fn  = (const float*)d_in[3];
    const int*   hf  = (const int*)d_in[4];
    float* out = (float*)d_out;

    char* ws = (char*)d_ws;
    float4*   Dws      = (float4*)(ws + 0);            // 8192*16   = 128 KB
    float4*   F        = (float4*)(ws + 131072);       // 4096*4*16 = 256 KB
    unsigned* pcount32 = (unsigned*)(ws + 393216);     // 64*2048*4 = 512 KB
    int*      done     = (int*)(ws + 917504);          // 4 B

    nn_all<<<1024, 256, 0, stream>>>(obj, sr, hv, fn, hf, out, Dws, F, done);
    ray_count<<<RAY_NB, 256, 0, stream>>>(obj, Dws, F, pcount32, done, out);
}

// Round 13
// 113.057 us; speedup vs baseline: 1.2053x; 1.2053x over previous
//
#include <hip/hip_runtime.h>
#include <math.h>

#define N_OBJ 8192
#define N_SR  4096
#define N_F   4096
#define EPSF  1e-8f
#define EPS2F 1e-16f

typedef float v2f __attribute__((ext_vector_type(2)));
static __device__ __forceinline__ v2f sp(float x) { v2f r; r.x = x; r.y = x; return r; }
static __device__ __forceinline__ v2f vfma(v2f a, v2f b, v2f c) { return __builtin_elementwise_fma(a, b, c); }

// ================= K1: NN (chunked sr, packed fp32) + face table ============
// 1024 blocks x 256 (4 blocks/CU). Each block: 8 obj points; sr staged in 4
// chunks of 1024 (16 KB LDS, pair-packed SoA). Each wave owns 2 points.
// argmin on shifted d2' = ss - 2*dot; ascending global index across chunks
// preserves jnp.argmin first-min tie rule.  [frozen since R11]
__global__ void __launch_bounds__(256) nn_all(const float* __restrict__ obj,
                                              const float* __restrict__ sr,
                                              const float* __restrict__ hv,
                                              const float* __restrict__ fn,
                                              const int* __restrict__ hf,
                                              float* __restrict__ out,
                                              float4* __restrict__ Dws,
                                              float4* __restrict__ F,
                                              int* __restrict__ done) {
    __shared__ float4 cXY[512];                    // (x0,x1,y0,y1)   8 KB
    __shared__ float4 cZS[512];                    // (z0,z1,ss0,ss1) 8 KB
    const int tid = threadIdx.x, b = blockIdx.x;
    const float2* sr2 = (const float2*)sr;

    if (b == 0 && tid == 0) done[0] = 0;
    if (tid < 4) {                                 // 4 faces per block
        const int f = b * 4 + tid;
        const int i0 = hf[3*f], i1 = hf[3*f+1], i2 = hf[3*f+2];
        const float v0x = hv[3*i0], v0y = hv[3*i0+1], v0z = hv[3*i0+2];
        const float v1x = hv[3*i1], v1y = hv[3*i1+1], v1z = hv[3*i1+2];
        const float v2x = hv[3*i2], v2y = hv[3*i2+1], v2z = hv[3*i2+2];
        const float nx = fn[3*f], ny = fn[3*f+1], nz = fn[3*f+2];
        F[4*f+0] = make_float4(nx, ny, nz, v0x*nx + v0y*ny + v0z*nz);
        {
            float ex = v1x-v0x, ey = v1y-v0y, ez = v1z-v0z;
            float cx = ny*ez-nz*ey, cy = nz*ex-nx*ez, cz = nx*ey-ny*ex;
            F[4*f+1] = make_float4(cx, cy, cz, v0x*cx + v0y*cy + v0z*cz);
        }
        {
            float ex = v2x-v1x, ey = v2y-v1y, ez = v2z-v1z;
            float cx = ny*ez-nz*ey, cy = nz*ex-nx*ez, cz = nx*ey-ny*ex;
            F[4*f+2] = make_float4(cx, cy, cz, v1x*cx + v1y*cy + v1z*cz);
        }
        {
            float ex = v0x-v2x, ey = v0y-v2y, ez = v0z-v2z;
            float cx = ny*ez-nz*ey, cy = nz*ex-nx*ez, cz = nx*ey-ny*ex;
            F[4*f+3] = make_float4(cx, cy, cz, v2x*cx + v2y*cy + v2z*cz);
        }
    }

    const int w = tid >> 6, lane = tid & 63;
    const int p0 = b * 8 + w * 2, p1 = p0 + 1;     // wave-uniform -> s_load

    const float ax = obj[3*p0], ay = obj[3*p0+1], az = obj[3*p0+2];
    const float bx = obj[3*p1], by = obj[3*p1+1], bz = obj[3*p1+2];
    const float aaa = fmaf(ax, ax, fmaf(ay, ay, az * az));
    const float aab = fmaf(bx, bx, fmaf(by, by, bz * bz));

    float a0 = INFINITY, a1 = INFINITY, c0v = INFINITY, c1v = INFINITY;
    int ai0 = 0, ai1 = 1, ci0 = 0, ci1 = 1;

    for (int c = 0; c < 4; ++c) {
        __syncthreads();                           // prev chunk fully consumed
        {
#pragma unroll
            for (int t = 0; t < 2; ++t) {
                int e = t * 256 + tid;             // 512 pairs per chunk
                int gp = c * 512 + e;
                float2 A = sr2[3 * gp], B = sr2[3 * gp + 1], C = sr2[3 * gp + 2];
                float x0 = A.x, y0 = A.y, z0 = B.x, x1 = B.y, y1 = C.x, z1 = C.y;
                cXY[e] = make_float4(x0, x1, y0, y1);
                cZS[e] = make_float4(z0, z1,
                                     fmaf(x0, x0, fmaf(y0, y0, z0 * z0)),
                                     fmaf(x1, x1, fmaf(y1, y1, z1 * z1)));
            }
        }
        __syncthreads();

        int e2 = c * 1024 + lane * 2;              // global idx of half-0
#pragma unroll
        for (int step = 0; step < 8; ++step) {
            int e = step * 64 + lane;
            float4 A = cXY[e];                     // 16B stride, conflict-free
            float4 B = cZS[e];
            v2f X; X.x = A.x; X.y = A.y;
            v2f Y; Y.x = A.z; Y.y = A.w;
            v2f Z; Z.x = B.x; Z.y = B.y;
            v2f SS; SS.x = B.z; SS.y = B.w;
            {
                v2f d  = vfma(Z, sp(az), vfma(Y, sp(ay), X * sp(ax)));
                v2f d2 = vfma(d, sp(-2.f), SS);
                bool q0 = d2.x < a0, q1 = d2.y < a1;
                a0 = q0 ? d2.x : a0;  ai0 = q0 ? e2     : ai0;
                a1 = q1 ? d2.y : a1;  ai1 = q1 ? e2 + 1 : ai1;
            }
            {
                v2f d  = vfma(Z, sp(bz), vfma(Y, sp(by), X * sp(bx)));
                v2f d2 = vfma(d, sp(-2.f), SS);
                bool q0 = d2.x < c0v, q1 = d2.y < c1v;
                c0v = q0 ? d2.x : c0v;  ci0 = q0 ? e2     : ci0;
                c1v = q1 ? d2.y : c1v;  ci1 = q1 ? e2 + 1 : ci1;
            }
            e2 += 128;
        }
    }

    float bdA = a0; int biA = ai0;
    if (a1 < bdA || (a1 == bdA && ai1 < biA)) { bdA = a1; biA = ai1; }
    float bdB = c0v; int biB = ci0;
    if (c1v < bdB || (c1v == bdB && ci1 < biB)) { bdB = c1v; biB = ci1; }
#pragma unroll
    for (int off = 32; off > 0; off >>= 1) {
        float d = __shfl_down(bdA, off);
        int   i = __shfl_down(biA, off);
        if (d < bdA || (d == bdA && i < biA)) { bdA = d; biA = i; }
        float e = __shfl_down(bdB, off);
        int   j = __shfl_down(biB, off);
        if (e < bdB || (e == bdB && j < biB)) { bdB = e; biB = j; }
    }
    if (lane == 0) {
        {
            float dx = sr[3*biA] - ax, dy = sr[3*biA+1] - ay, dz = sr[3*biA+2] - az;
            Dws[p0] = make_float4(dx, dy, dz, fmaf(dx, dx, fmaf(dy, dy, dz * dz)));
            float nn  = sqrtf(fmaxf(bdA + aaa, 0.f));
            float sig = 1.f / (1.f + expf(-100.f * nn));
            out[1 + p0] = 1.f - 2.f * (sig - 0.5f);
        }
        {
            float dx = sr[3*biB] - bx, dy = sr[3*biB+1] - by, dz = sr[3*biB+2] - bz;
            Dws[p1] = make_float4(dx, dy, dz, fmaf(dx, dx, fmaf(dy, dy, dz * dz)));
            float nn  = sqrtf(fmaxf(bdB + aab, 0.f));
            float sig = 1.f / (1.f + expf(-100.f * nn));
            out[1 + p1] = 1.f - 2.f * (sig - 0.5f);
        }
    }
}

// ================= K2: ray parity -> packed u32 counts (NO atomics) =========
// 1024 blocks = 8 pt-groups x 128 face-chunks (RFC=32, 2 KB LDS); 4 pts/thr.
// ppt=4 makes LDS/VALU ratio 192/(70*4)=0.69 -> VALU-bound (ppt=2 was
// LDS-throughput-bound: 4 ds_read_b128 x 12cyc per face-iter per wave).
// Obj loads: 3 coalesced float4/thread (4 consecutive points). Counts pack
// into one u32 store; byte layout == pcount[fc][pt].
// Sign-squared hit test (d2=denom^2>0, nd=num*denom):
//   |denom|>EPS <=> d2>EPS^2 ; t>EPS <=> nd-EPS*d2>0 ;
//   e_i>=0 <=> q_i = C_i.(o*d2 + nd*D) - s_i*d2 >= 0
#define RFC 32
__global__ void __launch_bounds__(256) ray_count(const float* __restrict__ obj,
                                                 const float4* __restrict__ Dws,
                                                 const float4* __restrict__ F,
                                                 unsigned* __restrict__ pcount32) {
    __shared__ float4 sF[RFC * 4];                 // 2 KB
    const int tid = threadIdx.x;
    const int pg = blockIdx.x & 7, fc = blockIdx.x >> 3;

    if (tid < RFC * 4) sF[tid] = (F + (size_t)fc * RFC * 4)[tid];

    float px[4], py[4], pz[4], qx[4], qy[4], qz[4];
    int cnt[4];
    {
        const float4* obj4 = (const float4*)obj;   // 1024 pts/group = 768 float4
        int base = pg * 768 + tid * 3;
        float4 A = obj4[base], B = obj4[base + 1], C = obj4[base + 2];
        px[0] = A.x; py[0] = A.y; pz[0] = A.z;
        px[1] = A.w; py[1] = B.x; pz[1] = B.y;
        px[2] = B.z; py[2] = B.w; pz[2] = C.x;
        px[3] = C.y; py[3] = C.z; pz[3] = C.w;
        int p4 = pg * 1024 + tid * 4;
#pragma unroll
        for (int h = 0; h < 4; ++h) {
            float4 D = Dws[p4 + h];
            qx[h] = D.x; qy[h] = D.y; qz[h] = D.z;
            cnt[h] = 0;
        }
    }
    __syncthreads();

    float4 nF0 = sF[0], nF1 = sF[1], nF2 = sF[2], nF3 = sF[3];
#pragma unroll 4
    for (int f = 0; f < RFC; ++f) {
        const float4 Fn = nF0, C1 = nF1, C2 = nF2, C3 = nF3;
        if (f + 1 < RFC) {                         // one-face register lookahead
            nF0 = sF[4*f+4]; nF1 = sF[4*f+5]; nF2 = sF[4*f+6]; nF3 = sF[4*f+7];
        }
#pragma unroll
        for (int h = 0; h < 4; ++h) {
            float denom = fmaf(Fn.z, qz[h], fmaf(Fn.y, qy[h], Fn.x * qx[h]));
            float num   = Fn.w - fmaf(Fn.z, pz[h], fmaf(Fn.y, py[h], Fn.x * px[h]));
            float d2 = denom * denom;
            float nd = num * denom;
            float wx = fmaf(px[h], d2, nd * qx[h]);
            float wy = fmaf(py[h], d2, nd * qy[h]);
            float wz = fmaf(pz[h], d2, nd * qz[h]);
            float q1 = fmaf(-C1.w, d2, fmaf(C1.z, wz, fmaf(C1.y, wy, C1.x * wx)));
            float q2 = fmaf(-C2.w, d2, fmaf(C2.z, wz, fmaf(C2.y, wy, C2.x * wx)));
            float q3 = fmaf(-C3.w, d2, fmaf(C3.z, wz, fmaf(C3.y, wy, C3.x * wx)));
            float tc = fmaf(-EPSF, d2, nd);        // t > EPS
            float dc = d2 - EPS2F;                 // |denom| > EPS
            float m  = fminf(fminf(q1, q2), fminf(q3, fminf(tc, dc)));
            cnt[h] += (m >= 0.f) ? 1 : 0;
        }
    }
    pcount32[(size_t)fc * 2048 + pg * 256 + tid] =
        (unsigned)cnt[0] | ((unsigned)cnt[1] << 8) |
        ((unsigned)cnt[2] << 16) | ((unsigned)cnt[3] << 24);
}

// ================= K3: parity + pen_dist (32 blocks, done-counter final) ====
#define NCH (N_F / RFC)                            // 128 chunks
__global__ void __launch_bounds__(256) finalize(const float4* __restrict__ Dws,
                                                const unsigned char* __restrict__ pcount,
                                                float* __restrict__ fpart,
                                                int* __restrict__ done,
                                                float* __restrict__ out) {
    __shared__ float wsum[4];
    const int tid = threadIdx.x;
    const int pt = blockIdx.x * 256 + tid;

    int c = 0;
#pragma unroll 8
    for (int fc = 0; fc < NCH; ++fc)
        c += pcount[(size_t)fc * N_OBJ + pt];      // coalesced byte loads
    float s = (c & 1) ? Dws[pt].w : 0.f;
#pragma unroll
    for (int off = 32; off > 0; off >>= 1) s += __shfl_down(s, off);
    if ((tid & 63) == 0) wsum[tid >> 6] = s;
    __syncthreads();
    if (tid == 0) {
        fpart[blockIdx.x] = wsum[0] + wsum[1] + wsum[2] + wsum[3];
        __threadfence();
        if (atomicAdd(done, 1) == 31) {
            float tot = 0.f;
            for (int i = 0; i < 32; ++i)
                tot += atomicAdd(&fpart[i], 0.f);  // coherent reads, fixed order
            out[0] = sqrtf(tot + 1e-12f);
        }
    }
}

extern "C" void kernel_launch(void* const* d_in, const int* in_sizes, int n_in,
                              void* d_out, int out_size, void* d_ws, size_t ws_size,
                              hipStream_t stream) {
    const float* obj = (const float*)d_in[0];
    const float* sr  = (const float*)d_in[1];
    const float* hv  = (const float*)d_in[2];
    const float* fn  = (const float*)d_in[3];
    const int*   hf  = (const int*)d_in[4];
    float* out = (float*)d_out;

    char* ws = (char*)d_ws;
    float4*   Dws      = (float4*)(ws + 0);            // 8192*16    = 128 KB
    float4*   F        = (float4*)(ws + 131072);       // 4096*4*16  = 256 KB
    unsigned* pcount32 = (unsigned*)(ws + 393216);     // 128*2048*4 =   1 MB
    float*    fpart    = (float*)(ws + 1441792);       // 128 B
    int*      done     = (int*)(ws + 1441920);         // 4 B

    nn_all<<<1024, 256, 0, stream>>>(obj, sr, hv, fn, hf, out, Dws, F, done);
    ray_count<<<1024, 256, 0, stream>>>(obj, Dws, F, pcount32);
    finalize<<<32, 256, 0, stream>>>(Dws, (const unsigned char*)pcount32, fpart, done, out);
}